// Round 6
// baseline (1415.424 us; speedup 1.0000x reference)
//
#include <hip/hip_runtime.h>
#include <stdint.h>

typedef __attribute__((ext_vector_type(8))) short short8;
typedef __attribute__((ext_vector_type(4))) float f32x4;
typedef unsigned short ushort_t;

#define T_STEPS 10
#define BT 64
#define WPACK_BYTES (2048*1024)                 // 2048 chunks x 1 KiB
#define VBUF_OFF  WPACK_BYTES
#define HBF_OFF   (WPACK_BYTES + 8192)
#define H_ELEMS   (8192ull*T_STEPS*512)
#define HBF_BYTES (H_ELEMS*2)

typedef const __attribute__((address_space(1))) void gas_void;
typedef __attribute__((address_space(3))) void las_void;

__device__ __forceinline__ void gld_lds16(const void* g, void* l){
  __builtin_amdgcn_global_load_lds((gas_void*)g, (las_void*)l, 16, 0, 0);
}

__device__ __forceinline__ unsigned int pk2(float x, float y){
  unsigned int bx = __float_as_uint(x), by = __float_as_uint(y);
  bx = (bx + 0x7FFFu + ((bx>>16)&1u)) >> 16;     // RNE fp32->bf16
  by = (by + 0x7FFFu + ((by>>16)&1u)) >> 16;
  return bx | (by<<16);
}
__device__ __forceinline__ float sigf(float x){ return 1.f/(1.f + __expf(-x)); }
__device__ __forceinline__ float tanh_(float x){
  x = fminf(fmaxf(x, -15.f), 15.f);
  float e = __expf(2.f*x);
  return (e - 1.f)/(e + 1.f);
}

// ---- K0a: pack W_hh [2048][512] fp32 -> bf16 ------------------------------
// chunk = (((js*8 + w)*4 + g)*2 + n)*16 + kc ; in-chunk lane = khi*16 + jl
// j = js*256 + w*32 + n*16 + jl ; k = kc*32 + khi*8 ..
__global__ __launch_bounds__(256) void k_pack(const float* __restrict__ Whh,
                                              ushort_t* __restrict__ wp){
  int id  = blockIdx.x*256 + threadIdx.x;   // 0..131071
  int row = id >> 6;                        // gate-col 0..2047
  int ko  = (id & 63) * 8;                  // k offset 0..504
  const float* p = Whh + row*512 + ko;
  float4 a = *(const float4*)p, b = *(const float4*)(p+4);
  uint4 v;
  v.x = pk2(a.x,a.y); v.y = pk2(a.z,a.w);
  v.z = pk2(b.x,b.y); v.w = pk2(b.z,b.w);
  int g = row >> 9, j = row & 511;
  int js = j >> 8, w = (j >> 5) & 7, n = (j >> 4) & 1, jl = j & 15;
  int kc = ko >> 5, khi = (ko >> 3) & 3, lane = khi*16 + jl;
  int chunk = (((js*8 + w)*4 + g)*2 + n)*16 + kc;
  *(uint4*)(wp + chunk*512 + lane*8) = v;
}

// ---- K0b: v[j] = sum_h fc2[h]*fc1[h][j]; bias0 = fc2.fc1_b + fc2_b --------
__global__ __launch_bounds__(256) void k_v(const float* __restrict__ fc1w,
                                           const float* __restrict__ fc1b,
                                           const float* __restrict__ fc2w,
                                           const float* __restrict__ fc2b,
                                           float* __restrict__ vout,
                                           float* __restrict__ bias0){
  __shared__ float red[4][64];
  int tid = threadIdx.x;
  if (blockIdx.x < 16){
    int j  = blockIdx.x*64 + (tid & 63);
    int hc = tid >> 6;
    float s = 0.f;
    for (int hh = hc*128; hh < hc*128 + 128; ++hh)
      s += fc2w[hh] * fc1w[hh*1024 + j];
    red[hc][tid & 63] = s;
    __syncthreads();
    if (tid < 64)
      vout[blockIdx.x*64 + tid] = red[0][tid]+red[1][tid]+red[2][tid]+red[3][tid];
  } else {
    if (tid < 64){
      float s = 0.f;
      for (int i = 0; i < 8; ++i){ int hh = i*64 + tid; s += fc2w[hh]*fc1b[hh]; }
      for (int m = 32; m; m >>= 1) s += __shfl_xor(s, m);
      if (tid == 0) *bias0 = s + fc2b[0];
    }
  }
}

// ---- K2: out[b] = h[b,9,:].v2 + bias0 (overwrite -> deterministic init) ---
__global__ __launch_bounds__(512) void k_init(const float* __restrict__ h,
                                              const float* __restrict__ v,
                                              const float* __restrict__ bias0,
                                              float* __restrict__ out){
  int w = threadIdx.x >> 6, lane = threadIdx.x & 63;
  float b0v = *bias0;
  const float* v2 = v + 512;
  for (int r = 0; r < 8; ++r){
    int b = blockIdx.x*64 + w*8 + r;
    const float* hp = h + ((size_t)b*T_STEPS + 9)*512 + lane*8;
    float4 x0 = *(const float4*)hp, x1 = *(const float4*)(hp+4);
    const float* vp = v2 + lane*8;
    float4 w0 = *(const float4*)vp, w1 = *(const float4*)(vp+4);
    float s = x0.x*w0.x + x0.y*w0.y + x0.z*w0.z + x0.w*w0.w
            + x1.x*w1.x + x1.y*w1.y + x1.z*w1.z + x1.w*w1.w;
    for (int m = 32; m; m >>= 1) s += __shfl_xor(s, m);
    if (lane == 0) out[b] = s + b0v;
  }
}

// ---- K0c: h fp32 -> bf16 (linear). grid = H_ELEMS/16/256 = 10240 ----------
__global__ __launch_bounds__(256) void k_prep(const float* __restrict__ h,
                                              ushort_t* __restrict__ hbf){
  size_t id = (size_t)blockIdx.x*256 + threadIdx.x;
  if (id*16 >= H_ELEMS) return;
  const float* p = h + id*16;
  float4 a = *(const float4*)p,     b = *(const float4*)(p+4);
  float4 c = *(const float4*)(p+8), d = *(const float4*)(p+12);
  uint4 lo, hi;
  lo.x = pk2(a.x,a.y); lo.y = pk2(a.z,a.w); lo.z = pk2(b.x,b.y); lo.w = pk2(b.z,b.w);
  hi.x = pk2(c.x,c.y); hi.y = pk2(c.z,c.w); hi.z = pk2(d.x,d.y); hi.w = pk2(d.z,d.w);
  uint4* q = (uint4*)(hbf + id*16);
  q[0] = lo; q[1] = hi;
}

// ---- staging: 8 waves, 8 rows each, pre-swizzled source (rule #21) --------
__device__ __forceinline__ void stage_async(ushort_t* dst, const ushort_t* hbf,
                                            int b0, int t, int w, int lane){
#pragma unroll
  for (int i = 0; i < 8; ++i){
    int row = i*8 + w;
    const ushort_t* src = hbf + ((size_t)(b0 + row)*T_STEPS + t)*512
                        + ((lane ^ (row & 7)) << 3);
    gld_lds16(src, dst + row*512);
  }
}

__device__ __forceinline__ void stage_sync(ushort_t* dst, const float* h,
                                           int b0, int t, int tid){
  int row = tid >> 3, sub = tid & 7;       // 8 threads per 512-elem row
  const float* hp = h + ((size_t)(b0 + row)*T_STEPS + t)*512;
#pragma unroll
  for (int i = 0; i < 8; ++i){
    int q = sub*8 + i;                     // 8-short group index 0..63
    const float* p = hp + q*8;
    float4 x0 = *(const float4*)p, x1 = *(const float4*)(p+4);
    uint4 pk;
    pk.x = pk2(x0.x,x0.y); pk.y = pk2(x0.z,x0.w);
    pk.z = pk2(x1.x,x1.y); pk.w = pk2(x1.z,x1.w);
    *(uint4*)&dst[row*512 + ((q ^ (row & 7)) << 3)] = pk;
  }
}

// ---- one serialized gate pass: K=512 GEMM for gate G, then epilogue EP -----
// EP: 0 tg=tanh(g) ; 1 tg=sig(i)*tg ; 2 cst=sig(f)*cst+tg ; 3 part+=sig(o)*tanh(cst)*v1
template<int G, int EP>
__device__ __forceinline__ void pass(
    const ushort_t* __restrict__ Ac, const short8* __restrict__ Wg,
    const float* __restrict__ ysl, int t,
    int llo, int lhi,
    const float (&bias2)[4][2], const float (&wihv)[4][2], const float (&v1v)[2],
    float (&tg)[4][2][4], float (&cst)[4][2][4], float (&part)[4][4])
{
  f32x4 acc[4][2];
#pragma unroll
  for (int m=0;m<4;++m)
#pragma unroll
    for (int n=0;n<2;++n) acc[m][n] = (f32x4){0.f,0.f,0.f,0.f};

  short8 bb[4][2];                         // ring-4: prefetch distance 3
#pragma unroll
  for (int p=0; p<3; ++p)
#pragma unroll
    for (int n=0; n<2; ++n)
      bb[p][n] = Wg[(n*16 + p)*64];

#pragma unroll
  for (int kc=0; kc<16; ++kc){
    if (kc < 13){
#pragma unroll
      for (int n=0; n<2; ++n)
        bb[(kc+3)&3][n] = Wg[(n*16 + kc+3)*64];
    }
    short8 af[4];
#pragma unroll
    for (int m=0; m<4; ++m)
      af[m] = *(const short8*)&Ac[(m*16 + llo)*512 + (((kc*4 + lhi) ^ (llo&7)) << 3)];
#pragma unroll
    for (int n=0; n<2; ++n)
#pragma unroll
      for (int m=0; m<4; ++m)
        acc[m][n] = __builtin_amdgcn_mfma_f32_16x16x32_bf16(
            af[m], bb[kc&3][n], acc[m][n], 0, 0, 0);
  }

#pragma unroll
  for (int m=0;m<4;++m)
#pragma unroll
    for (int r=0;r<4;++r){
      float yr = ysl[(m*16 + lhi*4 + r)*T_STEPS + t];   // LDS broadcast read
#pragma unroll
      for (int n=0;n<2;++n){
        float pre = acc[m][n][r] + fmaf(yr, wihv[G][n], bias2[G][n]);
        if constexpr (EP == 0) tg[m][n][r] = tanh_(pre);
        if constexpr (EP == 1) tg[m][n][r] = sigf(pre) * tg[m][n][r];
        if constexpr (EP == 2) cst[m][n][r] = sigf(pre)*cst[m][n][r] + tg[m][n][r];
        if constexpr (EP == 3) part[m][r] += sigf(pre)*tanh_(cst[m][n][r])*v1v[n];
      }
    }
}

// ---- K1: fused gates GEMM + LSTM scan + d.v1 contribution ------------------
template<bool PREP>
__global__ __launch_bounds__(512, 2)
void k_main(const float* __restrict__ h, const ushort_t* __restrict__ hbf,
            const float* __restrict__ y,
            const float* __restrict__ Wih, const float* __restrict__ bih,
            const float* __restrict__ bhh,
            const ushort_t* __restrict__ wpack_us, const float* __restrict__ v1,
            float* __restrict__ out)
{
  __shared__ __align__(16) ushort_t As[2][BT*512];   // 128 KiB
  __shared__ float ys[BT*T_STEPS];                   // 640 floats
  int tid = threadIdx.x;
  int w = tid >> 6, lane = tid & 63, lhi = lane >> 4, llo = lane & 15;
  int bid = blockIdx.x;
  int tile = (bid & 7) | ((bid >> 4) << 3);     // js-siblings (bid, bid+8) same XCD
  int js   = (bid >> 3) & 1;
  int b0 = tile * BT;

  // wave-uniform W base for this (js, w); per-gate base = + G*32 chunks (*64 short8)
  const short8* Wbase = (const short8*)wpack_us + (size_t)(js*8 + w)*4*32*64 + lane;

  float bias2[4][2], wihv[4][2], v1v[2];
  int jcb = js*256 + w*32 + llo;
#pragma unroll
  for (int g=0; g<4; ++g)
#pragma unroll
    for (int n=0; n<2; ++n){
      int col = g*512 + jcb + n*16;
      bias2[g][n] = bih[col] + bhh[col];
      wihv[g][n]  = Wih[col];
    }
#pragma unroll
  for (int n=0; n<2; ++n) v1v[n] = v1[jcb + n*16];

  float cst[4][2][4], tg[4][2][4], part[4][4];
#pragma unroll
  for (int m=0;m<4;++m){
#pragma unroll
    for (int n=0;n<2;++n)
#pragma unroll
      for (int r=0;r<4;++r){ cst[m][n][r] = 0.f; tg[m][n][r] = 0.f; }
#pragma unroll
    for (int r=0;r<4;++r) part[m][r] = 0.f;
  }

  // R5 BUG FIX: BT*T_STEPS = 640 > 512 threads -> strided loop, full coverage
  for (int i = tid; i < BT*T_STEPS; i += 512)
    ys[i] = y[(size_t)b0*T_STEPS + i];

  if constexpr (PREP) stage_async(&As[0][0], hbf, b0, 0, w, lane);
  else                stage_sync (&As[0][0], h,   b0, 0, tid);
  __syncthreads();

#pragma unroll 1
  for (int t=0; t<T_STEPS; ++t){
    const ushort_t* Ac = PREP ? &As[t & 1][0] : &As[0][0];
    if constexpr (PREP){
      if (t < T_STEPS-1) stage_async(&As[(t+1)&1][0], hbf, b0, t+1, w, lane);
    }

    // serialized gates: g(tanh) -> i -> f -> o(last step only)
    pass<2,0>(Ac, Wbase + 2*32*64, ys, t, llo, lhi, bias2, wihv, v1v, tg, cst, part);
    pass<0,1>(Ac, Wbase + 0*32*64, ys, t, llo, lhi, bias2, wihv, v1v, tg, cst, part);
    pass<1,2>(Ac, Wbase + 1*32*64, ys, t, llo, lhi, bias2, wihv, v1v, tg, cst, part);
    if (t == T_STEPS-1)
      pass<3,3>(Ac, Wbase + 3*32*64, ys, t, llo, lhi, bias2, wihv, v1v, tg, cst, part);

    __syncthreads();
    if constexpr (!PREP){
      if (t < T_STEPS-1){
        stage_sync(&As[0][0], h, b0, t+1, tid);
        __syncthreads();
      }
    }
  }

#pragma unroll
  for (int m=0;m<4;++m)
#pragma unroll
    for (int r=0;r<4;++r){
      float val = part[m][r];
      val += __shfl_xor(val, 1);
      val += __shfl_xor(val, 2);
      val += __shfl_xor(val, 4);
      val += __shfl_xor(val, 8);
      if (llo == 0) atomicAdd(&out[b0 + m*16 + lhi*4 + r], val);
    }
}

extern "C" void kernel_launch(void* const* d_in, const int* in_sizes, int n_in,
                              void* d_out, int out_size, void* d_ws, size_t ws_size,
                              hipStream_t stream){
  (void)in_sizes; (void)n_in; (void)out_size;
  const float* h    = (const float*)d_in[0];
  const float* y    = (const float*)d_in[1];
  // d_in[2..7] = attention weights: mathematically dead (softmax over size-1 dim == 1)
  const float* Wih  = (const float*)d_in[8];
  const float* Whh  = (const float*)d_in[9];
  const float* bih  = (const float*)d_in[10];
  const float* bhh  = (const float*)d_in[11];
  const float* fc1w = (const float*)d_in[12];
  const float* fc1b = (const float*)d_in[13];
  const float* fc2w = (const float*)d_in[14];
  const float* fc2b = (const float*)d_in[15];
  float* out = (float*)d_out;

  ushort_t* wpack = (ushort_t*)d_ws;
  float* vbuf  = (float*)((char*)d_ws + VBUF_OFF);
  float* bias0 = vbuf + 1024;
  ushort_t* hbf = (ushort_t*)((char*)d_ws + HBF_OFF);
  bool prep = ws_size >= (size_t)HBF_OFF + HBF_BYTES;

  k_pack<<<512, 256, 0, stream>>>(Whh, wpack);
  k_v<<<17, 256, 0, stream>>>(fc1w, fc1b, fc2w, fc2b, vbuf, bias0);
  if (prep){
    int prep_blocks = (int)(H_ELEMS / 16 / 256);   // = 10240, exact
    k_prep<<<prep_blocks, 256, 0, stream>>>(h, hbf);
  }
  k_init<<<128, 512, 0, stream>>>(h, vbuf, bias0, out);
  if (prep)
    k_main<true ><<<256, 512, 0, stream>>>(h, hbf, y, Wih, bih, bhh, wpack, vbuf, out);
  else
    k_main<false><<<256, 512, 0, stream>>>(h, hbf, y, Wih, bih, bhh, wpack, vbuf, out);
}

// Round 7
// 287.696 us; speedup vs baseline: 4.9199x; 4.9199x over previous
//
#include <hip/hip_runtime.h>
#include <stdint.h>

typedef __attribute__((ext_vector_type(8))) short short8;
typedef __attribute__((ext_vector_type(4))) float f32x4;
typedef unsigned short ushort_t;

#define T_STEPS 10
#define BT  128                                 // batch rows per block
#define JPB 128                                 // j columns per block
#define WPACK_BYTES (2048*1024)                 // 2048 chunks x 1 KiB
#define VBUF_OFF  WPACK_BYTES
#define HBF_OFF   (WPACK_BYTES + 8192)
#define H_ELEMS   (8192ull*T_STEPS*512)
#define HBF_BYTES (H_ELEMS*2)

typedef const __attribute__((address_space(1))) void gas_void;
typedef __attribute__((address_space(3))) void las_void;

__device__ __forceinline__ void gld_lds16(const void* g, void* l){
  __builtin_amdgcn_global_load_lds((gas_void*)g, (las_void*)l, 16, 0, 0);
}

__device__ __forceinline__ unsigned int pk2(float x, float y){
  unsigned int bx = __float_as_uint(x), by = __float_as_uint(y);
  bx = (bx + 0x7FFFu + ((bx>>16)&1u)) >> 16;     // RNE fp32->bf16
  by = (by + 0x7FFFu + ((by>>16)&1u)) >> 16;
  return bx | (by<<16);
}
__device__ __forceinline__ float sigf(float x){ return 1.f/(1.f + __expf(-x)); }
__device__ __forceinline__ float tanh_(float x){
  x = fminf(fmaxf(x, -15.f), 15.f);
  float e = __expf(2.f*x);
  return (e - 1.f)/(e + 1.f);
}

// ---- K0a: pack W_hh [2048][512] fp32 -> bf16 B-fragment chunks -------------
// chunk = ((jb*8 + jt)*4 + g)*16 + kc ; in-chunk lane = khi*16 + jl
// j = jb*128 + jt*16 + jl ; k = kc*32 + khi*8 .. +8
__global__ __launch_bounds__(256) void k_pack(const float* __restrict__ Whh,
                                              ushort_t* __restrict__ wp){
  int id  = blockIdx.x*256 + threadIdx.x;   // 0..131071
  int row = id >> 6;                        // gate-col 0..2047
  int ko  = (id & 63) * 8;                  // k offset 0..504
  const float* p = Whh + row*512 + ko;
  float4 a = *(const float4*)p, b = *(const float4*)(p+4);
  uint4 v;
  v.x = pk2(a.x,a.y); v.y = pk2(a.z,a.w);
  v.z = pk2(b.x,b.y); v.w = pk2(b.z,b.w);
  int g = row >> 9, j = row & 511;
  int jb = j >> 7, jt = (j >> 4) & 7, jl = j & 15;
  int kc = ko >> 5, khi = (ko >> 3) & 3, lane = khi*16 + jl;
  int chunk = ((jb*8 + jt)*4 + g)*16 + kc;
  *(uint4*)(wp + chunk*512 + lane*8) = v;
}

// ---- K0b: v[j] = sum_h fc2[h]*fc1[h][j]; bias0 = fc2.fc1_b + fc2_b --------
__global__ __launch_bounds__(256) void k_v(const float* __restrict__ fc1w,
                                           const float* __restrict__ fc1b,
                                           const float* __restrict__ fc2w,
                                           const float* __restrict__ fc2b,
                                           float* __restrict__ vout,
                                           float* __restrict__ bias0){
  __shared__ float red[4][64];
  int tid = threadIdx.x;
  if (blockIdx.x < 16){
    int j  = blockIdx.x*64 + (tid & 63);
    int hc = tid >> 6;
    float s = 0.f;
    for (int hh = hc*128; hh < hc*128 + 128; ++hh)
      s += fc2w[hh] * fc1w[hh*1024 + j];
    red[hc][tid & 63] = s;
    __syncthreads();
    if (tid < 64)
      vout[blockIdx.x*64 + tid] = red[0][tid]+red[1][tid]+red[2][tid]+red[3][tid];
  } else {
    if (tid < 64){
      float s = 0.f;
      for (int i = 0; i < 8; ++i){ int hh = i*64 + tid; s += fc2w[hh]*fc1b[hh]; }
      for (int m = 32; m; m >>= 1) s += __shfl_xor(s, m);
      if (tid == 0) *bias0 = s + fc2b[0];
    }
  }
}

// ---- K2: out[b] = h[b,9,:].v2 + bias0 (overwrite -> deterministic init) ---
__global__ __launch_bounds__(512) void k_init(const float* __restrict__ h,
                                              const float* __restrict__ v,
                                              const float* __restrict__ bias0,
                                              float* __restrict__ out){
  int w = threadIdx.x >> 6, lane = threadIdx.x & 63;
  float b0v = *bias0;
  const float* v2 = v + 512;
  for (int r = 0; r < 8; ++r){
    int b = blockIdx.x*64 + w*8 + r;
    const float* hp = h + ((size_t)b*T_STEPS + 9)*512 + lane*8;
    float4 x0 = *(const float4*)hp, x1 = *(const float4*)(hp+4);
    const float* vp = v2 + lane*8;
    float4 w0 = *(const float4*)vp, w1 = *(const float4*)(vp+4);
    float s = x0.x*w0.x + x0.y*w0.y + x0.z*w0.z + x0.w*w0.w
            + x1.x*w1.x + x1.y*w1.y + x1.z*w1.z + x1.w*w1.w;
    for (int m = 32; m; m >>= 1) s += __shfl_xor(s, m);
    if (lane == 0) out[b] = s + b0v;
  }
}

// ---- K0c: h fp32 -> bf16 (linear). grid = H_ELEMS/16/256 = 10240 ----------
__global__ __launch_bounds__(256) void k_prep(const float* __restrict__ h,
                                              ushort_t* __restrict__ hbf){
  size_t id = (size_t)blockIdx.x*256 + threadIdx.x;
  if (id*16 >= H_ELEMS) return;
  const float* p = h + id*16;
  float4 a = *(const float4*)p,     b = *(const float4*)(p+4);
  float4 c = *(const float4*)(p+8), d = *(const float4*)(p+12);
  uint4 lo, hi;
  lo.x = pk2(a.x,a.y); lo.y = pk2(a.z,a.w); lo.z = pk2(b.x,b.y); lo.w = pk2(b.z,b.w);
  hi.x = pk2(c.x,c.y); hi.y = pk2(c.z,c.w); hi.z = pk2(d.x,d.y); hi.w = pk2(d.z,d.w);
  uint4* q = (uint4*)(hbf + id*16);
  q[0] = lo; q[1] = hi;
}

// ---- per-slice staging: A(t,kc) 8KB + W(gate-set,kc) into LDS dbuf --------
// A layout: [128 rows][32 k] linear (row*64B, k-group lhi*16B)
// W layout: [g][jt] chunks of 1KB (lane*16B)
__device__ __forceinline__ void stage_prep(
    ushort_t* ab, ushort_t* wb, const ushort_t* __restrict__ hbf,
    const ushort_t* __restrict__ wpack, int b0, int jb, int s, int w, int lane)
{
  int t  = (s < 160) ? (s >> 4) : 9;
  int kc = s & 15;
  {
    int row = w*16 + (lane >> 2), qa = lane & 3;
    const ushort_t* src = hbf + ((size_t)(b0+row)*T_STEPS + t)*512 + kc*32 + qa*8;
    gld_lds16(src, ab + w*512);                    // HW: base + lane*16
  }
  if (s < 160){
#pragma unroll
    for (int i = 0; i < 3; ++i){
      int cw = w*3 + i, g = cw >> 3, jt = cw & 7;
      const ushort_t* src = wpack + ((size_t)((jb*8+jt)*4+g)*16 + kc)*512 + lane*8;
      gld_lds16(src, wb + (g*8+jt)*512);
    }
  } else {
    int jt = w;
    const ushort_t* src = wpack + ((size_t)((jb*8+jt)*4+3)*16 + kc)*512 + lane*8;
    gld_lds16(src, wb + jt*512);
  }
}

__device__ __forceinline__ void stage_sync(
    ushort_t* ab, ushort_t* wb, const float* __restrict__ h,
    const ushort_t* __restrict__ wpack, int b0, int jb, int s,
    int tid, int w, int lane)
{
  int t  = (s < 160) ? (s >> 4) : 9;
  int kc = s & 15;
  {
    int row = tid >> 2, qa = tid & 3;
    const float* p = h + ((size_t)(b0+row)*T_STEPS + t)*512 + kc*32 + qa*8;
    float4 x0 = *(const float4*)p, x1 = *(const float4*)(p+4);
    uint4 pk;
    pk.x = pk2(x0.x,x0.y); pk.y = pk2(x0.z,x0.w);
    pk.z = pk2(x1.x,x1.y); pk.w = pk2(x1.z,x1.w);
    *(uint4*)(ab + row*32 + qa*8) = pk;
  }
  if (s < 160){
#pragma unroll
    for (int i = 0; i < 3; ++i){
      int cw = w*3 + i, g = cw >> 3, jt = cw & 7;
      const ushort_t* src = wpack + ((size_t)((jb*8+jt)*4+g)*16 + kc)*512 + lane*8;
      gld_lds16(src, wb + (g*8+jt)*512);
    }
  } else {
    int jt = w;
    const ushort_t* src = wpack + ((size_t)((jb*8+jt)*4+3)*16 + kc)*512 + lane*8;
    gld_lds16(src, wb + jt*512);
  }
}

// ---- K1: slice-pipelined fused gates GEMM + LSTM scan ----------------------
template<bool PREP>
__global__ __launch_bounds__(512) __attribute__((amdgpu_waves_per_eu(2)))
void k_main(const float* __restrict__ h, const ushort_t* __restrict__ hbf,
            const float* __restrict__ y,
            const float* __restrict__ Wih, const float* __restrict__ bih,
            const float* __restrict__ bhh,
            const ushort_t* __restrict__ wpack, const float* __restrict__ v1,
            float* __restrict__ out)
{
  __shared__ __align__(16) ushort_t Ab[2][BT*32];     // 2 x 8 KiB
  __shared__ __align__(16) ushort_t Wb[2][24*512];    // 2 x 24 KiB
  __shared__ float ys[BT*T_STEPS];                    // 5 KiB

  int tid = threadIdx.x;
  int w = tid >> 6, lane = tid & 63, lhi = lane >> 4, llo = lane & 15;
  int mh = w & 1, wj = w >> 1;                        // wave grid 2(m) x 4(j)
  int bid = blockIdx.x;
  int xcd = bid & 7, q = bid >> 3;
  int tile = xcd*8 + (q >> 2), jb = q & 3;            // 4 j-siblings same XCD
  int b0 = tile * BT;

  float bias2[4][2], wihv[4][2];
#pragma unroll
  for (int g = 0; g < 4; ++g)
#pragma unroll
    for (int n = 0; n < 2; ++n){
      int col = g*512 + jb*128 + (wj*2+n)*16 + llo;
      bias2[g][n] = bih[col] + bhh[col];
      wihv[g][n]  = Wih[col];
    }

  // y tile (strided: 1280 > 512 threads — R5 lesson)
  for (int i = tid; i < BT*T_STEPS; i += 512)
    ys[i] = y[(size_t)b0*T_STEPS + i];

  if constexpr (PREP) stage_prep(Ab[0], Wb[0], hbf, wpack, b0, jb, 0, w, lane);
  else                stage_sync(Ab[0], Wb[0], h,   wpack, b0, jb, 0, tid, w, lane);
  __syncthreads();

  float cst[4][2][4];
  f32x4 acc[4][3][2];
#pragma unroll
  for (int m = 0; m < 4; ++m)
#pragma unroll
    for (int n = 0; n < 2; ++n){
#pragma unroll
      for (int r = 0; r < 4; ++r) cst[m][n][r] = 0.f;
#pragma unroll
      for (int g = 0; g < 3; ++g) acc[m][g][n] = (f32x4){0.f,0.f,0.f,0.f};
    }

  // ---- phase 1: i,f,g-tilde sweeps, 160 slices (t 0..9 x kc 0..15) --------
#pragma unroll 1
  for (int s = 0; s < 160; ++s){
    int ns = s + 1;
    if constexpr (PREP) stage_prep(Ab[ns&1], Wb[ns&1], hbf, wpack, b0, jb, ns, w, lane);
    else                stage_sync(Ab[ns&1], Wb[ns&1], h,   wpack, b0, jb, ns, tid, w, lane);

    const ushort_t* ab = Ab[s&1];
    const ushort_t* wb = Wb[s&1];
    short8 af[4];
#pragma unroll
    for (int m = 0; m < 4; ++m){
      int row = mh*64 + m*16 + llo;
      af[m] = *(const short8*)(ab + row*32 + lhi*8);
    }
    short8 wf[3][2];
#pragma unroll
    for (int g = 0; g < 3; ++g)
#pragma unroll
      for (int n = 0; n < 2; ++n)
        wf[g][n] = *(const short8*)(wb + ((g*8 + wj*2 + n) << 9) + lane*8);
#pragma unroll
    for (int g = 0; g < 3; ++g)
#pragma unroll
      for (int n = 0; n < 2; ++n)
#pragma unroll
        for (int m = 0; m < 4; ++m)
          acc[m][g][n] = __builtin_amdgcn_mfma_f32_16x16x32_bf16(
              af[m], wf[g][n], acc[m][g][n], 0, 0, 0);

    if ((s & 15) == 15){                       // end of K: cell update
      int t = s >> 4;
#pragma unroll
      for (int m = 0; m < 4; ++m)
#pragma unroll
        for (int r = 0; r < 4; ++r){
          float yr = ys[(mh*64 + m*16 + lhi*4 + r)*T_STEPS + t];
#pragma unroll
          for (int n = 0; n < 2; ++n){
            float pi = acc[m][0][n][r] + fmaf(yr, wihv[0][n], bias2[0][n]);
            float pf = acc[m][1][n][r] + fmaf(yr, wihv[1][n], bias2[1][n]);
            float pg = acc[m][2][n][r] + fmaf(yr, wihv[2][n], bias2[2][n]);
            cst[m][n][r] = sigf(pf)*cst[m][n][r] + sigf(pi)*tanh_(pg);
          }
        }
#pragma unroll
      for (int m = 0; m < 4; ++m)
#pragma unroll
        for (int g = 0; g < 3; ++g)
#pragma unroll
          for (int n = 0; n < 2; ++n) acc[m][g][n] = (f32x4){0.f,0.f,0.f,0.f};
    }
    __syncthreads();
  }

  // ---- phase 2: o-gate sweep at t=9 (16 slices), reuses A(9,kc) -----------
  f32x4 acco[4][2];
#pragma unroll
  for (int m = 0; m < 4; ++m)
#pragma unroll
    for (int n = 0; n < 2; ++n) acco[m][n] = (f32x4){0.f,0.f,0.f,0.f};

#pragma unroll 1
  for (int s = 160; s < 176; ++s){
    if (s < 175){
      int ns = s + 1;
      if constexpr (PREP) stage_prep(Ab[ns&1], Wb[ns&1], hbf, wpack, b0, jb, ns, w, lane);
      else                stage_sync(Ab[ns&1], Wb[ns&1], h,   wpack, b0, jb, ns, tid, w, lane);
    }
    const ushort_t* ab = Ab[s&1];
    const ushort_t* wb = Wb[s&1];
    short8 af[4];
#pragma unroll
    for (int m = 0; m < 4; ++m){
      int row = mh*64 + m*16 + llo;
      af[m] = *(const short8*)(ab + row*32 + lhi*8);
    }
    short8 wo[2];
#pragma unroll
    for (int n = 0; n < 2; ++n)
      wo[n] = *(const short8*)(wb + ((wj*2 + n) << 9) + lane*8);
#pragma unroll
    for (int n = 0; n < 2; ++n)
#pragma unroll
      for (int m = 0; m < 4; ++m)
        acco[m][n] = __builtin_amdgcn_mfma_f32_16x16x32_bf16(
            af[m], wo[n], acco[m][n], 0, 0, 0);
    __syncthreads();
  }

  // ---- epilogue: part = sig(o)*tanh(c)*v1, reduce over j, atomic ----------
  float v1v[2];
#pragma unroll
  for (int n = 0; n < 2; ++n) v1v[n] = v1[jb*128 + (wj*2+n)*16 + llo];

#pragma unroll
  for (int m = 0; m < 4; ++m)
#pragma unroll
    for (int r = 0; r < 4; ++r){
      float yr = ys[(mh*64 + m*16 + lhi*4 + r)*T_STEPS + 9];
      float val = 0.f;
#pragma unroll
      for (int n = 0; n < 2; ++n){
        float po = acco[m][n][r] + fmaf(yr, wihv[3][n], bias2[3][n]);
        val += sigf(po)*tanh_(cst[m][n][r])*v1v[n];
      }
      val += __shfl_xor(val, 1);
      val += __shfl_xor(val, 2);
      val += __shfl_xor(val, 4);
      val += __shfl_xor(val, 8);
      if (llo == 0)
        atomicAdd(&out[b0 + mh*64 + m*16 + lhi*4 + r], val);
    }
}

extern "C" void kernel_launch(void* const* d_in, const int* in_sizes, int n_in,
                              void* d_out, int out_size, void* d_ws, size_t ws_size,
                              hipStream_t stream){
  (void)in_sizes; (void)n_in; (void)out_size;
  const float* h    = (const float*)d_in[0];
  const float* y    = (const float*)d_in[1];
  // d_in[2..7] = attention weights: mathematically dead (softmax over size-1 dim == 1)
  const float* Wih  = (const float*)d_in[8];
  const float* Whh  = (const float*)d_in[9];
  const float* bih  = (const float*)d_in[10];
  const float* bhh  = (const float*)d_in[11];
  const float* fc1w = (const float*)d_in[12];
  const float* fc1b = (const float*)d_in[13];
  const float* fc2w = (const float*)d_in[14];
  const float* fc2b = (const float*)d_in[15];
  float* out = (float*)d_out;

  ushort_t* wpack = (ushort_t*)d_ws;
  float* vbuf  = (float*)((char*)d_ws + VBUF_OFF);
  float* bias0 = vbuf + 1024;
  ushort_t* hbf = (ushort_t*)((char*)d_ws + HBF_OFF);
  bool prep = ws_size >= (size_t)HBF_OFF + HBF_BYTES;

  k_pack<<<512, 256, 0, stream>>>(Whh, wpack);
  k_v<<<17, 256, 0, stream>>>(fc1w, fc1b, fc2w, fc2b, vbuf, bias0);
  if (prep){
    int prep_blocks = (int)(H_ELEMS / 16 / 256);   // = 10240, exact
    k_prep<<<prep_blocks, 256, 0, stream>>>(h, hbf);
  }
  k_init<<<128, 512, 0, stream>>>(h, vbuf, bias0, out);
  if (prep)
    k_main<true ><<<256, 512, 0, stream>>>(h, hbf, y, Wih, bih, bhh, wpack, vbuf, out);
  else
    k_main<false><<<256, 512, 0, stream>>>(h, hbf, y, Wih, bih, bhh, wpack, vbuf, out);
}